// Round 16
// baseline (309.378 us; speedup 1.0000x reference)
//
#include <hip/hip_runtime.h>
#include <hip/hip_fp16.h>
#include <cstdint>
#include <cstddef>

#define B_ 512
#define T_ 256
#define N_ 128
#define H_ 64
#define G_ 256  // 4H

typedef __attribute__((ext_vector_type(8))) short short8;
typedef __attribute__((ext_vector_type(4))) float f32x4;
typedef _Float16 half2_t __attribute__((ext_vector_type(2)));

static __device__ __forceinline__ unsigned short f2bf(float f) {
    union { float f; unsigned int i; } v;
    v.f = f;
    unsigned int x = v.i;
    return (unsigned short)((x + 0x7fffu + ((x >> 16) & 1u)) >> 16);  // RNE
}
static __device__ __forceinline__ half2_t u2h2(unsigned int u) {
    union { unsigned int u; half2_t h; } v; v.u = u; return v.h;
}

// ---------------------------------------------------------------------------
// K0b: pack W_hh -> bf16 MFMA B-fragments in PER-LANE order.
// wp[(q*2+kk)*256 + tid] = short8{ bf16(W_hh[g][kk*32+rq*8+e]) }, where
// g = q*64 + (tid>>6)*16 + (tid&15), rq = (tid&63)>>4.  k_rnn14 asm-loads
// these 8 uint4 per thread -> weights are STRUCTURALLY un-sinkable and no
// convert chain exists inside the recurrence kernel at all.
// ---------------------------------------------------------------------------
__global__ __launch_bounds__(256) void k_wpack2(const float* __restrict__ W_hh,
                                                uint4* __restrict__ wp) {
    int idx = blockIdx.x * 256 + threadIdx.x;   // 2048 entries x 16B = 32 KB
    if (idx >= 2048) return;
    int slot = idx >> 8;          // q*2+kk
    int tid  = idx & 255;
    int q = slot >> 1, kk = slot & 1;
    int w = tid >> 6, lane = tid & 63;
    int cc = lane & 15, rq = lane >> 4;
    int g = q * 64 + w * 16 + cc;
    const float* src = W_hh + (size_t)g * H_ + kk * 32 + rq * 8;
    union { uint4 u; unsigned short s[8]; } pk;
    #pragma unroll
    for (int e = 0; e < 8; ++e) pk.s[e] = f2bf(src[e]);
    wp[idx] = pk.u;
}

// ---------------------------------------------------------------------------
// K1+K2 fused (unchanged: ~48us). gatesx layout: [b][t][cell][gate i,f,g,o].
// ---------------------------------------------------------------------------
__global__ __launch_bounds__(256) void k_awgemm(const float* __restrict__ x,
                                                const float* __restrict__ attn_w,
                                                const float* __restrict__ W_ih,
                                                const float* __restrict__ b_ih,
                                                const float* __restrict__ b_hh,
                                                float* __restrict__ iw,
                                                _Float16* __restrict__ gatesx) {
    __shared__ __align__(16) unsigned short Wl[G_][136];  // bf16 W_ih, padded
    __shared__ __align__(16) unsigned short Al[32][136];  // bf16 wx tile (overlaid: red)
    __shared__ float bias[G_];
    __shared__ float aw_s[T_];
    __shared__ float a_s[N_];
    __shared__ float wred[4];
    const int tid = threadIdx.x;
    const int b = blockIdx.x;

    for (int q = tid; q < G_ * 32; q += 256) {
        int r = q >> 5, c4 = (q & 31) << 2;
        float4 v = *(const float4*)(W_ih + r * N_ + c4);
        Wl[r][c4 + 0] = f2bf(v.x); Wl[r][c4 + 1] = f2bf(v.y);
        Wl[r][c4 + 2] = f2bf(v.z); Wl[r][c4 + 3] = f2bf(v.w);
    }
    bias[tid] = b_ih[tid] + b_hh[tid];
    aw_s[tid] = attn_w[2 * H_ + tid];
    __syncthreads();

    // ---- Phase A: attention softmax (shift-invariance kills h/c/bias) ----
    float (*red)[128] = (float(*)[128])&Al[0][0];
    const int n0 = (tid & 31) << 2;
    const int tg = tid >> 5;
    const float* xb = x + (size_t)b * (T_ * N_);
    {
        float p0 = 0.f, p1 = 0.f, p2 = 0.f, p3 = 0.f;
        for (int t = tg; t < T_; t += 8) {
            float4 v = *(const float4*)(xb + t * N_ + n0);
            float w = aw_s[t];
            p0 += v.x * w; p1 += v.y * w; p2 += v.z * w; p3 += v.w * w;
        }
        red[tg][n0 + 0] = p0; red[tg][n0 + 1] = p1;
        red[tg][n0 + 2] = p2; red[tg][n0 + 3] = p3;
    }
    __syncthreads();
    {
        float s = 0.f;
        if (tid < 128) {
            #pragma unroll
            for (int g = 0; g < 8; ++g) s += red[g][tid];
        }
        float m = (tid < 128) ? s : -1e30f;
        #pragma unroll
        for (int d = 1; d < 64; d <<= 1) m = fmaxf(m, __shfl_xor(m, d));
        if ((tid & 63) == 0) wred[tid >> 6] = m;
        __syncthreads();
        m = fmaxf(wred[0], wred[1]);
        __syncthreads();
        float e = (tid < 128) ? __expf(s - m) : 0.f;
        float z = e;
        #pragma unroll
        for (int d = 1; d < 64; d <<= 1) z += __shfl_xor(z, d);
        if ((tid & 63) == 0) wred[tid >> 6] = z;
        __syncthreads();
        z = wred[0] + wred[1];
        if (tid < 128) a_s[tid] = e / z;
    }
    __syncthreads();

    // ---- Phase B: weighting + MFMA GEMM ----
    const int lane = tid & 63;
    const int lr = lane & 15;
    const int lk = (lane >> 4) << 3;
    const int gc0 = (tid >> 6) << 6;
    const int orow = (lane >> 4) << 2;

    for (int st = 0; st < 8; ++st) {
        const int r0 = b * T_ + st * 32;
        __syncthreads();
        for (int q = tid; q < 32 * 32; q += 256) {
            int r = q >> 5, c4 = (q & 31) << 2;
            size_t off = (size_t)(r0 + r) * N_ + c4;
            float4 v = *(const float4*)(x + off);
            float4 w;
            w.x = a_s[c4 + 0] * v.x; w.y = a_s[c4 + 1] * v.y;
            w.z = a_s[c4 + 2] * v.z; w.w = a_s[c4 + 3] * v.w;
            *(float4*)(iw + off) = w;            // output 0 (f32, exact)
            Al[r][c4 + 0] = f2bf(w.x); Al[r][c4 + 1] = f2bf(w.y);
            Al[r][c4 + 2] = f2bf(w.z); Al[r][c4 + 3] = f2bf(w.w);
        }
        __syncthreads();

        f32x4 acc[2][4];
        #pragma unroll
        for (int mt = 0; mt < 2; ++mt)
            #pragma unroll
            for (int nt = 0; nt < 4; ++nt)
                acc[mt][nt] = (f32x4){0.f, 0.f, 0.f, 0.f};

        #pragma unroll
        for (int kk = 0; kk < N_; kk += 32) {
            short8 af0 = *(const short8*)(&Al[lr][kk + lk]);
            short8 af1 = *(const short8*)(&Al[16 + lr][kk + lk]);
            #pragma unroll
            for (int nt = 0; nt < 4; ++nt) {
                short8 bfv = *(const short8*)(&Wl[gc0 + nt * 16 + lr][kk + lk]);
                acc[0][nt] = __builtin_amdgcn_mfma_f32_16x16x32_bf16(af0, bfv, acc[0][nt], 0, 0, 0);
                acc[1][nt] = __builtin_amdgcn_mfma_f32_16x16x32_bf16(af1, bfv, acc[1][nt], 0, 0, 0);
            }
        }
        // D: col = gc0+nt*16+lr (gate index), row = mt*16+(lane>>4)*4+reg
        #pragma unroll
        for (int mt = 0; mt < 2; ++mt) {
            #pragma unroll
            for (int nt = 0; nt < 4; ++nt) {
                int col = gc0 + nt * 16 + lr;
                float bs = bias[col];
                int cell = col & 63, qg = col >> 6;
                #pragma unroll
                for (int rg = 0; rg < 4; ++rg) {
                    int rr = r0 + mt * 16 + orow + rg;
                    gatesx[((size_t)rr * H_ + cell) * 4 + qg] =
                        (_Float16)(acc[mt][nt][rg] + bs);
                }
            }
        }
    }
}

// ---------------------------------------------------------------------------
// K3: MFMA LSTM recurrence, 16 batches/block, 32 blocks x 256 thr.
// Round-15 failure: VGPR_Count=60 < the 90+ needed -> compiler sank the
// bfrag load+convert chain into the t-loop (round-3/6 failure mode again);
// the MFMA structure never actually ran with resident weights.
// Fix (proven in round 7): weights come from k_wpack2 PRE-PACKED in lane
// order and are loaded via asm volatile global_load_dwordx4 -- asm dests
// cannot be rematerialized, forcing 32 weight VGPRs live. No f2bf chain
// remains in this kernel. Rest identical: raw s_barrier + lgkmcnt(0)-only
// (enc stores + gate prefetch stay in flight), double-buffered h, one
// barrier/step, named SA/SB depth-2 prefetch.
// ---------------------------------------------------------------------------
__global__ __launch_bounds__(256)
void k_rnn14(const _Float16* __restrict__ gatesx,
             const uint4* __restrict__ wp,
             float* __restrict__ enc) {
    __shared__ unsigned short hb[2][16][72];   // bf16 h, double-buffered, 144B rows
    const int tid = threadIdx.x;
    const int bg = blockIdx.x;       // batch group of 16
    const int w = tid >> 6;
    const int lane = tid & 63;
    const int cc = lane & 15;
    const int rq = lane >> 4;
    const int j = w * 16 + cc;       // gate cell owned by this thread

    // 8 x asm dwordx4 = 32 forced-live VGPRs of bf16 B-fragments
    uint4 bf[4][2];
    #pragma unroll
    for (int q = 0; q < 4; ++q) {
        #pragma unroll
        for (int kk = 0; kk < 2; ++kk) {
            unsigned voff = (unsigned)((((q << 1) + kk) * 256 + tid) << 4);
            asm volatile("global_load_dwordx4 %0, %1, %2"
                         : "=v"(bf[q][kk]) : "v"(voff), "s"(wp) : "memory");
        }
    }
    asm volatile("s_waitcnt vmcnt(0)" ::: "memory");

    // zero hb[1] (t=0 reads buf 1)
    {
        unsigned short* p = &hb[0][0][0];
        for (int q2 = tid; q2 < 16 * 72; q2 += 256) p[16 * 72 + q2] = 0;
    }

    size_t gb[4]; float* ep[4];
    #pragma unroll
    for (int rg = 0; rg < 4; ++rg) {
        int brow = bg * 16 + rq * 4 + rg;
        gb[rg] = (size_t)brow * T_ * G_ + j * 4;
        ep[rg] = enc + (size_t)brow * T_ * H_ + j;
    }
    uint2 SA[4], SB[4];
    #pragma unroll
    for (int rg = 0; rg < 4; ++rg) {
        SA[rg] = *(const uint2*)(gatesx + gb[rg]);        // t = 0
        SB[rg] = *(const uint2*)(gatesx + gb[rg] + G_);   // t = 1
    }
    float cs[4] = {0.f, 0.f, 0.f, 0.f};
    __syncthreads();   // once (prologue drain ok)

#define FRAG(Q, KK) (*(const short8*)&bf[Q][KK])

#define STEP(SL, TCUR, TNEXT, RB, WB)                                       \
    {                                                                       \
        f32x4 acc[4];                                                       \
        _Pragma("unroll")                                                   \
        for (int rg = 0; rg < 4; ++rg) {                                    \
            half2_t hif = u2h2(SL[rg].x), hgo = u2h2(SL[rg].y);             \
            acc[0][rg] = (float)hif.x; acc[1][rg] = (float)hif.y;           \
            acc[2][rg] = (float)hgo.x; acc[3][rg] = (float)hgo.y;           \
        }                                                                   \
        int tn_ = (TNEXT) < T_ ? (TNEXT) : (T_ - 1);                        \
        _Pragma("unroll")                                                   \
        for (int rg = 0; rg < 4; ++rg)                                      \
            SL[rg] = *(const uint2*)(gatesx + gb[rg] + (size_t)tn_ * G_);   \
        short8 a0 = *(const short8*)(&hb[RB][cc][rq * 8]);                  \
        short8 a1 = *(const short8*)(&hb[RB][cc][32 + rq * 8]);             \
        _Pragma("unroll")                                                   \
        for (int q = 0; q < 4; ++q) {                                       \
            acc[q] = __builtin_amdgcn_mfma_f32_16x16x32_bf16(a0, FRAG(q, 0), acc[q], 0, 0, 0); \
            acc[q] = __builtin_amdgcn_mfma_f32_16x16x32_bf16(a1, FRAG(q, 1), acc[q], 0, 0, 0); \
        }                                                                   \
        _Pragma("unroll")                                                   \
        for (int rg = 0; rg < 4; ++rg) {                                    \
            float ig = acc[0][rg], fg = acc[1][rg];                         \
            float gg = acc[2][rg], og = acc[3][rg];                         \
            float si = 1.f / (1.f + __expf(-ig));                           \
            float sf = 1.f / (1.f + __expf(-fg));                           \
            float tg2 = 1.f - 2.f / (__expf(2.f * gg) + 1.f);               \
            float so = 1.f / (1.f + __expf(-og));                           \
            cs[rg] = sf * cs[rg] + si * tg2;                                \
            float tc = 1.f - 2.f / (__expf(2.f * cs[rg]) + 1.f);            \
            float hv_ = so * tc;                                            \
            hb[WB][rq * 4 + rg][j] = f2bf(hv_);                             \
            ep[rg][(size_t)(TCUR) * H_] = hv_;                              \
        }                                                                   \
        __builtin_amdgcn_sched_barrier(0);                                  \
        asm volatile("s_waitcnt lgkmcnt(0)");                               \
        __builtin_amdgcn_sched_barrier(0);                                  \
        __builtin_amdgcn_s_barrier();                                       \
        __builtin_amdgcn_sched_barrier(0);                                  \
    }

    for (int t = 0; t < T_; t += 2) {
        STEP(SA, t, t + 2, 1, 0);
        STEP(SB, t + 1, t + 3, 0, 1);
    }
#undef STEP
#undef FRAG
}

extern "C" void kernel_launch(void* const* d_in, const int* in_sizes, int n_in,
                              void* d_out, int out_size, void* d_ws, size_t ws_size,
                              hipStream_t stream) {
    if (n_in < 7 || in_sizes[0] != B_ * T_ * N_) return;

    const float* x    = (const float*)d_in[0];
    const float* aw   = (const float*)d_in[1];
    // d_in[2] (attn_b) provably cancels in the softmax — unused.
    const float* W_ih = (const float*)d_in[3];
    const float* W_hh = (const float*)d_in[4];
    const float* b_ih = (const float*)d_in[5];
    const float* b_hh = (const float*)d_in[6];

    float* iwp = (float*)d_out;                          // (B,T,N) f32
    float* enc = (float*)d_out + (size_t)B_ * T_ * N_;   // (B,T,H) f32

    size_t gx_bytes = (size_t)B_ * T_ * G_ * sizeof(_Float16);   // 33.5 MB
    _Float16* gatesx = (_Float16*)d_ws;
    uint4* wp = (uint4*)((char*)d_ws + gx_bytes);                // 32 KB
    size_t need = gx_bytes + 2048 * sizeof(uint4);
    if (ws_size < need) return;  // fail loudly rather than corrupt

    hipLaunchKernelGGL(k_wpack2, dim3(8), dim3(256), 0, stream, W_hh, wp);
    hipLaunchKernelGGL(k_awgemm, dim3(B_), dim3(256), 0, stream,
                       x, aw, W_ih, b_ih, b_hh, iwp, gatesx);
    hipLaunchKernelGGL(k_rnn14, dim3(B_ / 16), dim3(256), 0, stream,
                       gatesx, wp, enc);
}

// Round 17
// 291.691 us; speedup vs baseline: 1.0606x; 1.0606x over previous
//
#include <hip/hip_runtime.h>
#include <hip/hip_fp16.h>
#include <cstdint>
#include <cstddef>

#define B_ 512
#define T_ 256
#define N_ 128
#define H_ 64
#define G_ 256  // 4H

typedef __attribute__((ext_vector_type(8))) short short8;
typedef __attribute__((ext_vector_type(4))) float f32x4;
typedef _Float16 half2_t __attribute__((ext_vector_type(2)));

static __device__ __forceinline__ unsigned short f2bf(float f) {
    union { float f; unsigned int i; } v;
    v.f = f;
    unsigned int x = v.i;
    return (unsigned short)((x + 0x7fffu + ((x >> 16) & 1u)) >> 16);  // RNE
}
static __device__ __forceinline__ half2_t u2h2(unsigned int u) {
    union { unsigned int u; half2_t h; } v; v.u = u; return v.h;
}

// ---------------------------------------------------------------------------
// K0b: pack W_hh -> bf16 MFMA B-fragments in PER-LANE order.
// wp[(q*2+kk)*256 + tid] = short8{ bf16(W_hh[g][kk*32+rq*8+e]) }, where
// g = q*64 + (tid>>6)*16 + (tid&15), rq = (tid&63)>>4.
// ---------------------------------------------------------------------------
__global__ __launch_bounds__(256) void k_wpack2(const float* __restrict__ W_hh,
                                                uint4* __restrict__ wp) {
    int idx = blockIdx.x * 256 + threadIdx.x;   // 2048 entries x 16B = 32 KB
    if (idx >= 2048) return;
    int slot = idx >> 8;          // q*2+kk
    int tid  = idx & 255;
    int q = slot >> 1, kk = slot & 1;
    int w = tid >> 6, lane = tid & 63;
    int cc = lane & 15, rq = lane >> 4;
    int g = q * 64 + w * 16 + cc;
    const float* src = W_hh + (size_t)g * H_ + kk * 32 + rq * 8;
    union { uint4 u; unsigned short s[8]; } pk;
    #pragma unroll
    for (int e = 0; e < 8; ++e) pk.s[e] = f2bf(src[e]);
    wp[idx] = pk.u;
}

// ---------------------------------------------------------------------------
// K1+K2 fused (unchanged: ~48us). gatesx layout: [b][t][cell][gate i,f,g,o].
// ---------------------------------------------------------------------------
__global__ __launch_bounds__(256) void k_awgemm(const float* __restrict__ x,
                                                const float* __restrict__ attn_w,
                                                const float* __restrict__ W_ih,
                                                const float* __restrict__ b_ih,
                                                const float* __restrict__ b_hh,
                                                float* __restrict__ iw,
                                                _Float16* __restrict__ gatesx) {
    __shared__ __align__(16) unsigned short Wl[G_][136];  // bf16 W_ih, padded
    __shared__ __align__(16) unsigned short Al[32][136];  // bf16 wx tile (overlaid: red)
    __shared__ float bias[G_];
    __shared__ float aw_s[T_];
    __shared__ float a_s[N_];
    __shared__ float wred[4];
    const int tid = threadIdx.x;
    const int b = blockIdx.x;

    for (int q = tid; q < G_ * 32; q += 256) {
        int r = q >> 5, c4 = (q & 31) << 2;
        float4 v = *(const float4*)(W_ih + r * N_ + c4);
        Wl[r][c4 + 0] = f2bf(v.x); Wl[r][c4 + 1] = f2bf(v.y);
        Wl[r][c4 + 2] = f2bf(v.z); Wl[r][c4 + 3] = f2bf(v.w);
    }
    bias[tid] = b_ih[tid] + b_hh[tid];
    aw_s[tid] = attn_w[2 * H_ + tid];
    __syncthreads();

    // ---- Phase A: attention softmax (shift-invariance kills h/c/bias) ----
    float (*red)[128] = (float(*)[128])&Al[0][0];
    const int n0 = (tid & 31) << 2;
    const int tg = tid >> 5;
    const float* xb = x + (size_t)b * (T_ * N_);
    {
        float p0 = 0.f, p1 = 0.f, p2 = 0.f, p3 = 0.f;
        for (int t = tg; t < T_; t += 8) {
            float4 v = *(const float4*)(xb + t * N_ + n0);
            float w = aw_s[t];
            p0 += v.x * w; p1 += v.y * w; p2 += v.z * w; p3 += v.w * w;
        }
        red[tg][n0 + 0] = p0; red[tg][n0 + 1] = p1;
        red[tg][n0 + 2] = p2; red[tg][n0 + 3] = p3;
    }
    __syncthreads();
    {
        float s = 0.f;
        if (tid < 128) {
            #pragma unroll
            for (int g = 0; g < 8; ++g) s += red[g][tid];
        }
        float m = (tid < 128) ? s : -1e30f;
        #pragma unroll
        for (int d = 1; d < 64; d <<= 1) m = fmaxf(m, __shfl_xor(m, d));
        if ((tid & 63) == 0) wred[tid >> 6] = m;
        __syncthreads();
        m = fmaxf(wred[0], wred[1]);
        __syncthreads();
        float e = (tid < 128) ? __expf(s - m) : 0.f;
        float z = e;
        #pragma unroll
        for (int d = 1; d < 64; d <<= 1) z += __shfl_xor(z, d);
        if ((tid & 63) == 0) wred[tid >> 6] = z;
        __syncthreads();
        z = wred[0] + wred[1];
        if (tid < 128) a_s[tid] = e / z;
    }
    __syncthreads();

    // ---- Phase B: weighting + MFMA GEMM ----
    const int lane = tid & 63;
    const int lr = lane & 15;
    const int lk = (lane >> 4) << 3;
    const int gc0 = (tid >> 6) << 6;
    const int orow = (lane >> 4) << 2;

    for (int st = 0; st < 8; ++st) {
        const int r0 = b * T_ + st * 32;
        __syncthreads();
        for (int q = tid; q < 32 * 32; q += 256) {
            int r = q >> 5, c4 = (q & 31) << 2;
            size_t off = (size_t)(r0 + r) * N_ + c4;
            float4 v = *(const float4*)(x + off);
            float4 w;
            w.x = a_s[c4 + 0] * v.x; w.y = a_s[c4 + 1] * v.y;
            w.z = a_s[c4 + 2] * v.z; w.w = a_s[c4 + 3] * v.w;
            *(float4*)(iw + off) = w;            // output 0 (f32, exact)
            Al[r][c4 + 0] = f2bf(w.x); Al[r][c4 + 1] = f2bf(w.y);
            Al[r][c4 + 2] = f2bf(w.z); Al[r][c4 + 3] = f2bf(w.w);
        }
        __syncthreads();

        f32x4 acc[2][4];
        #pragma unroll
        for (int mt = 0; mt < 2; ++mt)
            #pragma unroll
            for (int nt = 0; nt < 4; ++nt)
                acc[mt][nt] = (f32x4){0.f, 0.f, 0.f, 0.f};

        #pragma unroll
        for (int kk = 0; kk < N_; kk += 32) {
            short8 af0 = *(const short8*)(&Al[lr][kk + lk]);
            short8 af1 = *(const short8*)(&Al[16 + lr][kk + lk]);
            #pragma unroll
            for (int nt = 0; nt < 4; ++nt) {
                short8 bfv = *(const short8*)(&Wl[gc0 + nt * 16 + lr][kk + lk]);
                acc[0][nt] = __builtin_amdgcn_mfma_f32_16x16x32_bf16(af0, bfv, acc[0][nt], 0, 0, 0);
                acc[1][nt] = __builtin_amdgcn_mfma_f32_16x16x32_bf16(af1, bfv, acc[1][nt], 0, 0, 0);
            }
        }
        // D: col = gc0+nt*16+lr (gate index), row = mt*16+(lane>>4)*4+reg
        #pragma unroll
        for (int mt = 0; mt < 2; ++mt) {
            #pragma unroll
            for (int nt = 0; nt < 4; ++nt) {
                int col = gc0 + nt * 16 + lr;
                float bs = bias[col];
                int cell = col & 63, qg = col >> 6;
                #pragma unroll
                for (int rg = 0; rg < 4; ++rg) {
                    int rr = r0 + mt * 16 + orow + rg;
                    gatesx[((size_t)rr * H_ + cell) * 4 + qg] =
                        (_Float16)(acc[mt][nt][rg] + bs);
                }
            }
        }
    }
}

// ---------------------------------------------------------------------------
// K3: MFMA LSTM recurrence, 16 batches/block, 32 blocks x 256 thr.
// Round-16 failure decoded: asm dests can't be REMATERIALIZED but they CAN be
// SPILLED -- with default launch bounds (8-waves/EU target, 64-VGPR budget)
// the allocator spilled all 32 weight VGPRs to scratch (VGPR_Count=60, dur
// identical to round-15's sunk-loads version). Round 7 worked because it had
// BOTH asm loads AND waves_per_eu(1,1). The complete recipe, applied here:
//   asm volatile global_load (no remat) + waves_per_eu(1,1) (512-VGPR
//   budget, no spill). Costs nothing: grid is 1 block/CU anyway.
// ---------------------------------------------------------------------------
__global__ __attribute__((amdgpu_flat_work_group_size(256, 256)))
__attribute__((amdgpu_waves_per_eu(1, 1)))
void k_rnn15(const _Float16* __restrict__ gatesx,
             const uint4* __restrict__ wp,
             float* __restrict__ enc) {
    __shared__ unsigned short hb[2][16][72];   // bf16 h, double-buffered, 144B rows
    const int tid = threadIdx.x;
    const int bg = blockIdx.x;       // batch group of 16
    const int w = tid >> 6;
    const int lane = tid & 63;
    const int cc = lane & 15;
    const int rq = lane >> 4;
    const int j = w * 16 + cc;       // gate cell owned by this thread

    // 8 x asm dwordx4 = 32 forced-live VGPRs of bf16 B-fragments
    uint4 bf[4][2];
    #pragma unroll
    for (int q = 0; q < 4; ++q) {
        #pragma unroll
        for (int kk = 0; kk < 2; ++kk) {
            unsigned voff = (unsigned)((((q << 1) + kk) * 256 + tid) << 4);
            asm volatile("global_load_dwordx4 %0, %1, %2"
                         : "=v"(bf[q][kk]) : "v"(voff), "s"(wp) : "memory");
        }
    }
    asm volatile("s_waitcnt vmcnt(0)" ::: "memory");

    // zero hb[1] (t=0 reads buf 1)
    {
        unsigned short* p = &hb[0][0][0];
        for (int q2 = tid; q2 < 16 * 72; q2 += 256) p[16 * 72 + q2] = 0;
    }

    size_t gb[4]; float* ep[4];
    #pragma unroll
    for (int rg = 0; rg < 4; ++rg) {
        int brow = bg * 16 + rq * 4 + rg;
        gb[rg] = (size_t)brow * T_ * G_ + j * 4;
        ep[rg] = enc + (size_t)brow * T_ * H_ + j;
    }
    uint2 SA[4], SB[4];
    #pragma unroll
    for (int rg = 0; rg < 4; ++rg) {
        SA[rg] = *(const uint2*)(gatesx + gb[rg]);        // t = 0
        SB[rg] = *(const uint2*)(gatesx + gb[rg] + G_);   // t = 1
    }
    float cs[4] = {0.f, 0.f, 0.f, 0.f};
    __syncthreads();   // once (prologue drain ok)

#define FRAG(Q, KK) (*(const short8*)&bf[Q][KK])

#define STEP(SL, TCUR, TNEXT, RB, WB)                                       \
    {                                                                       \
        f32x4 acc[4];                                                       \
        _Pragma("unroll")                                                   \
        for (int rg = 0; rg < 4; ++rg) {                                    \
            half2_t hif = u2h2(SL[rg].x), hgo = u2h2(SL[rg].y);             \
            acc[0][rg] = (float)hif.x; acc[1][rg] = (float)hif.y;           \
            acc[2][rg] = (float)hgo.x; acc[3][rg] = (float)hgo.y;           \
        }                                                                   \
        int tn_ = (TNEXT) < T_ ? (TNEXT) : (T_ - 1);                        \
        _Pragma("unroll")                                                   \
        for (int rg = 0; rg < 4; ++rg)                                      \
            SL[rg] = *(const uint2*)(gatesx + gb[rg] + (size_t)tn_ * G_);   \
        short8 a0 = *(const short8*)(&hb[RB][cc][rq * 8]);                  \
        short8 a1 = *(const short8*)(&hb[RB][cc][32 + rq * 8]);             \
        _Pragma("unroll")                                                   \
        for (int q = 0; q < 4; ++q) {                                       \
            acc[q] = __builtin_amdgcn_mfma_f32_16x16x32_bf16(a0, FRAG(q, 0), acc[q], 0, 0, 0); \
            acc[q] = __builtin_amdgcn_mfma_f32_16x16x32_bf16(a1, FRAG(q, 1), acc[q], 0, 0, 0); \
        }                                                                   \
        _Pragma("unroll")                                                   \
        for (int rg = 0; rg < 4; ++rg) {                                    \
            float ig = acc[0][rg], fg = acc[1][rg];                         \
            float gg = acc[2][rg], og = acc[3][rg];                         \
            float si = 1.f / (1.f + __expf(-ig));                           \
            float sf = 1.f / (1.f + __expf(-fg));                           \
            float tg2 = 1.f - 2.f / (__expf(2.f * gg) + 1.f);               \
            float so = 1.f / (1.f + __expf(-og));                           \
            cs[rg] = sf * cs[rg] + si * tg2;                                \
            float tc = 1.f - 2.f / (__expf(2.f * cs[rg]) + 1.f);            \
            float hv_ = so * tc;                                            \
            hb[WB][rq * 4 + rg][j] = f2bf(hv_);                             \
            ep[rg][(size_t)(TCUR) * H_] = hv_;                              \
        }                                                                   \
        __builtin_amdgcn_sched_barrier(0);                                  \
        asm volatile("s_waitcnt lgkmcnt(0)");                               \
        __builtin_amdgcn_sched_barrier(0);                                  \
        __builtin_amdgcn_s_barrier();                                       \
        __builtin_amdgcn_sched_barrier(0);                                  \
    }

    for (int t = 0; t < T_; t += 2) {
        STEP(SA, t, t + 2, 1, 0);
        STEP(SB, t + 1, t + 3, 0, 1);
    }
#undef STEP
#undef FRAG
}

extern "C" void kernel_launch(void* const* d_in, const int* in_sizes, int n_in,
                              void* d_out, int out_size, void* d_ws, size_t ws_size,
                              hipStream_t stream) {
    if (n_in < 7 || in_sizes[0] != B_ * T_ * N_) return;

    const float* x    = (const float*)d_in[0];
    const float* aw   = (const float*)d_in[1];
    // d_in[2] (attn_b) provably cancels in the softmax — unused.
    const float* W_ih = (const float*)d_in[3];
    const float* W_hh = (const float*)d_in[4];
    const float* b_ih = (const float*)d_in[5];
    const float* b_hh = (const float*)d_in[6];

    float* iwp = (float*)d_out;                          // (B,T,N) f32
    float* enc = (float*)d_out + (size_t)B_ * T_ * N_;   // (B,T,H) f32

    size_t gx_bytes = (size_t)B_ * T_ * G_ * sizeof(_Float16);   // 33.5 MB
    _Float16* gatesx = (_Float16*)d_ws;
    uint4* wp = (uint4*)((char*)d_ws + gx_bytes);                // 32 KB
    size_t need = gx_bytes + 2048 * sizeof(uint4);
    if (ws_size < need) return;  // fail loudly rather than corrupt

    hipLaunchKernelGGL(k_wpack2, dim3(8), dim3(256), 0, stream, W_hh, wp);
    hipLaunchKernelGGL(k_awgemm, dim3(B_), dim3(256), 0, stream,
                       x, aw, W_ih, b_ih, b_hh, iwp, gatesx);
    hipLaunchKernelGGL(k_rnn15, dim3(B_ / 16), dim3(256), 0, stream,
                       gatesx, wp, enc);
}